// Round 2
// baseline (625.659 us; speedup 1.0000x reference)
//
#include <hip/hip_runtime.h>
#include <hip/hip_cooperative_groups.h>

namespace cg = cooperative_groups;

#define B_ 8
#define C_ 128
#define L_ 4096
#define P_ 96
#define D_ 16

typedef __attribute__((ext_vector_type(8))) short short8;
typedef __attribute__((ext_vector_type(16))) float float16v;

__device__ __forceinline__ unsigned short f2bf(float f) {
  unsigned int u = __float_as_uint(f);
  u += 0x7fff + ((u >> 16) & 1);          // round-to-nearest-even
  return (unsigned short)(u >> 16);
}

// ---------------------------------------------------------------------------
// Workspace layout (bytes)
// ---------------------------------------------------------------------------
constexpr size_t OFF_H      = 0;                      // h  [B][C][L] f32 : 16 MB
constexpr size_t OFF_PSUM   = 16777216;               // [C][2] f32
constexpr size_t OFF_PSUMSQ = OFF_PSUM + 8192;
constexpr size_t OFF_SCALE  = OFF_PSUMSQ + 8192;      // [C] f32 (fallback path only)
constexpr size_t OFF_SHIFT  = OFF_SCALE + 512;
constexpr size_t OFF_WALLT  = OFF_SHIFT + 512;        // WallT [c][r] f32 64 KB
constexpr size_t OFF_BALL   = OFF_WALLT + 65536;      // [128] f32
constexpr size_t OFF_QT     = OFF_BALL + 512;         // [B][L][16] bf16 (q pre-scaled by log2e)
constexpr size_t OFF_KT     = OFF_QT + 1048576;       // [B][L][16] bf16
constexpr size_t OFF_V2     = OFF_KT + 1048576;       // v2t [B][L/16][96][16] bf16 : 6 MB

// ===========================================================================
// FUSED cooperative kernel: prep + conv + bn + proj + attn in ONE dispatch.
// 256 blocks x 512 threads = 1 block/CU (LDS 50688 B, all blocks co-resident).
// Phase math is identical to the verified 5-kernel pipeline; only the
// wave->work mapping changes (proj: 8 waves x 16 rows; attn: 2 m-slices x 64
// iters instead of 4 x 32).
// ===========================================================================
__global__ __launch_bounds__(512, 2) void k_fused(
    const float* __restrict__ x, const float* __restrict__ Wt,
    const float* __restrict__ gamma, const float* __restrict__ beta,
    const float* __restrict__ Wq, const float* __restrict__ bq,
    const float* __restrict__ Wk, const float* __restrict__ bk,
    const float* __restrict__ Wv, const float* __restrict__ bv,
    const float* __restrict__ W2, const float* __restrict__ b2,
    float* __restrict__ y,
    float* __restrict__ h, float* __restrict__ psum, float* __restrict__ psumsq,
    float* __restrict__ wallT, float* __restrict__ ball,
    unsigned short* __restrict__ qT, unsigned short* __restrict__ kT,
    unsigned short* __restrict__ v2t)
{
  cg::grid_group grid = cg::this_grid();

  // LDS aliasing map (max live: attn 48K+512; bn scale/shift live through proj)
  __shared__ __align__(16) char smem[50688];
  float4* xs4      = (float4*)smem;                 // conv: 4 KB
  float*  rs1      = (float*)(smem + 4096);         // conv: 8 f32
  float*  rs2      = (float*)(smem + 4160);
  float*  ls_scale = (float*)(smem + 49664);        // bn->proj: 128 f32
  float*  ls_shift = (float*)(smem + 50176);

  const int bid = blockIdx.x;
  const int tid = threadIdx.x;

  // ---- phase 0: prep (wave 0 only; overlaps nothing, ~2 us) -------------
  // r = bid>>1 (0..127), c = (bid&1)*64 + lane. rows 0..15=Wq, 16..31=Wk,
  // 32..127 = W2 @ Wv. bt annihilated by BN shift-invariance.
  if (tid < 64) {
    const int r = bid >> 1;
    const int c = (bid & 1) * 64 + tid;
    float wv;
    if (r < 16) {
      wv = Wq[r * C_ + c];
    } else if (r < 32) {
      wv = Wk[(r - 16) * C_ + c];
    } else {
      const int p = r - 32;
      float s = 0.f;
#pragma unroll 8
      for (int o = 0; o < C_; ++o) s += W2[p * C_ + o] * Wv[o * C_ + c];
      wv = s;
    }
    wallT[c * C_ + r] = wv;
    if (c == 0) {
      float bb;
      if (r < 16)      bb = bq[r];
      else if (r < 32) bb = bk[r - 16];
      else {
        const int p = r - 32;
        float s = 0.f;
#pragma unroll 8
        for (int o = 0; o < C_; ++o) s += W2[p * C_ + o] * bv[o];
        bb = s;
      }
      ball[r] = bb;
    }
  }

  // ---- phase 1: conv. o = bid>>1, l-tile = (bid&1)*2048 ------------------
  {
    const int o  = bid >> 1;
    const int lt = bid & 1;
    const int l  = lt * 2048 + tid * 4;

    if (tid < 256) xs4[tid] = ((const float4*)x)[tid];   // 1024 floats exactly
    __syncthreads();

    float4 acc[8];
#pragma unroll
    for (int bb = 0; bb < 8; ++bb) acc[bb] = (float4){0.f, 0.f, 0.f, 0.f};

    const float* wp = Wt + (size_t)o * L_ + l;
    const size_t stride = (size_t)C_ * L_;
    const int phase = (o + lt * 8) & 31;

    float4 wbuf[2][4];
#pragma unroll
    for (int q = 0; q < 4; ++q)
      wbuf[0][q] = *(const float4*)(wp + (size_t)(phase * 4 + q) * stride);

#pragma unroll 2
    for (int g = 0; g < 32; ++g) {
      const int cur = g & 1, nb = cur ^ 1;
      const int in4 = ((phase + g + 1) & 31) * 4;   // wraps: always valid
#pragma unroll
      for (int q = 0; q < 4; ++q)
        wbuf[nb][q] = *(const float4*)(wp + (size_t)(in4 + q) * stride);

      const int ic = (phase + g) & 31;
#pragma unroll
      for (int bb = 0; bb < 8; ++bb) {
        const float4 xb = xs4[bb * 32 + ic];   // wave-uniform addr: broadcast
        acc[bb].x += xb.x * wbuf[cur][0].x + xb.y * wbuf[cur][1].x + xb.z * wbuf[cur][2].x + xb.w * wbuf[cur][3].x;
        acc[bb].y += xb.x * wbuf[cur][0].y + xb.y * wbuf[cur][1].y + xb.z * wbuf[cur][2].y + xb.w * wbuf[cur][3].y;
        acc[bb].z += xb.x * wbuf[cur][0].z + xb.y * wbuf[cur][1].z + xb.z * wbuf[cur][2].z + xb.w * wbuf[cur][3].z;
        acc[bb].w += xb.x * wbuf[cur][0].w + xb.y * wbuf[cur][1].w + xb.z * wbuf[cur][2].w + xb.w * wbuf[cur][3].w;
      }
    }
    float s1 = 0.f, s2 = 0.f;
#pragma unroll
    for (int bb = 0; bb < 8; ++bb) {
      *(float4*)(h + ((size_t)(bb * C_ + o)) * L_ + l) = acc[bb];
      s1 += acc[bb].x + acc[bb].y + acc[bb].z + acc[bb].w;
      s2 += acc[bb].x * acc[bb].x + acc[bb].y * acc[bb].y
          + acc[bb].z * acc[bb].z + acc[bb].w * acc[bb].w;
    }
    for (int off = 1; off < 64; off <<= 1) {
      s1 += __shfl_xor(s1, off);
      s2 += __shfl_xor(s2, off);
    }
    if ((tid & 63) == 0) { rs1[tid >> 6] = s1; rs2[tid >> 6] = s2; }
    __syncthreads();
    if (tid == 0) {
      float a1 = 0.f, a2 = 0.f;
#pragma unroll
      for (int wv = 0; wv < 8; ++wv) { a1 += rs1[wv]; a2 += rs2[wv]; }
      psum[o * 2 + lt]   = a1;
      psumsq[o * 2 + lt] = a2;
    }
  }

  grid.sync();   // psum/wallT/ball/h visible everywhere

  // ---- phase 2: BN finalize, redundant per block, into LDS --------------
  if (tid < 128) {
    const float s1 = psum[tid * 2] + psum[tid * 2 + 1];
    const float s2 = psumsq[tid * 2] + psumsq[tid * 2 + 1];
    const float inv = 1.f / 32768.f;
    const float mean = s1 * inv;
    const float var  = s2 * inv - mean * mean;
    const float sc   = rsqrtf(var + 1e-5f) * gamma[tid];
    ls_scale[tid] = sc;
    ls_shift[tid] = beta[tid] - mean * sc;
  }
  __syncthreads();

  // ---- phase 3: proj, 2 tiles per block (8 waves x 16 rows each) --------
  for (int jj = 0; jj < 2; ++jj) {
    const int job = bid * 2 + jj;
    const int bb_ = job >> 6;
    const int lx  = job & 63;
    const int l0  = lx * 64;
    float* hn = (float*)smem;                       // [c][68] f32
    unsigned short* v2s = (unsigned short*)smem;    // reused: [p][72] bf16

    // stage + bn + relu: 128c x 64l tile (2048 float4, 512 thr x 4)
#pragma unroll
    for (int i = 0; i < 4; ++i) {
      const int idx = tid + i * 512;
      const int c = idx >> 4, lq = (idx & 15) * 4;
      const float4 hv = *(const float4*)(h + ((size_t)(bb_ * C_ + c)) * L_ + l0 + lq);
      const float sc = ls_scale[c], sh = ls_shift[c];
      float4 r;
      r.x = fmaxf(hv.x * sc + sh, 0.f);
      r.y = fmaxf(hv.y * sc + sh, 0.f);
      r.z = fmaxf(hv.z * sc + sh, 0.f);
      r.w = fmaxf(hv.w * sc + sh, 0.f);
      *(float4*)(hn + c * 68 + lq) = r;
    }
    __syncthreads();

    const int wu = __builtin_amdgcn_readfirstlane(tid) >> 6;  // wave id 0..7
    const int lane = tid & 63;
    const int l = l0 + lane;
    const int rb = wu * 16;

    float acc[16];
#pragma unroll
    for (int r = 0; r < 16; ++r) acc[r] = ball[rb + r];

#pragma unroll 4
    for (int c = 0; c < C_; ++c) {
      const float hv = hn[c * 68 + lane];
      const float* wrow = wallT + c * C_ + rb;      // wave-uniform: s_load
#pragma unroll
      for (int r = 0; r < 16; ++r) acc[r] += wrow[r] * hv;
    }
    __syncthreads();   // all waves done reading hn before LDS reuse

    if (wu == 0) {                // rows 0..15 = q (pre-scaled by log2e)
      const size_t row = (size_t)(bb_ * L_ + l) * D_;
      short8 v0, v1;
#pragma unroll
      for (int r = 0; r < 8; ++r) {
        v0[r] = (short)f2bf(acc[r] * 1.44269504f);
        v1[r] = (short)f2bf(acc[8 + r] * 1.44269504f);
      }
      *(short8*)(qT + row) = v0;  *(short8*)(qT + row + 8) = v1;
    } else if (wu == 1) {         // rows 16..31 = k
      const size_t row = (size_t)(bb_ * L_ + l) * D_;
      short8 v0, v1;
#pragma unroll
      for (int r = 0; r < 8; ++r) { v0[r] = (short)f2bf(acc[r]); v1[r] = (short)f2bf(acc[8 + r]); }
      *(short8*)(kT + row) = v0;  *(short8*)(kT + row + 8) = v1;
    } else {                      // rows 32..127 = v2 -> LDS bounce
      const int pbase = rb - 32;
#pragma unroll
      for (int r = 0; r < 16; ++r)
        v2s[(pbase + r) * 72 + lane] = f2bf(acc[r]);
    }
    __syncthreads();

    // v2 stores, m-tiled layout v2t[b][m/16][p][m%16]: 1536 uint2, 512 thr x 3
#pragma unroll
    for (int i = 0; i < 3; ++i) {
      const int j = tid + i * 512;
      const int mo4 = j & 3;
      const int jp = j >> 2;
      const int p = jp % 96;
      const int mtl = jp / 96;                       // 0..3
      const uint2 val = *(const uint2*)(v2s + p * 72 + mtl * 16 + mo4 * 4);
      *(uint2*)(v2t + ((size_t)((bb_ * (L_ / 16) + lx * 4 + mtl)) * P_ + p) * 16
                + mo4 * 4) = val;
    }
    __syncthreads();  // LDS reused by next jj / attn
  }

  grid.sync();   // qT/kT/v2t visible everywhere

  // ---- phase 4: attn. b = bid>>5, l0 = (bid&31)*128 ---------------------
  // 8 waves: qg = w&3 (4 q-groups x 32 rows), ms = w>>2 (2 m-slices x 2048).
  {
    const int b  = bid >> 5;
    const int l0 = (bid & 31) * 128;
    float* ldsO = (float*)smem;                 // [p][l] 48 KB
    float* ldsL = (float*)(smem + 49152);       // [128]

#pragma unroll
    for (int i = 0; i < 24; ++i) ldsO[tid + i * 512] = 0.f;
    if (tid < 128) ldsL[tid] = 0.f;
    __syncthreads();

    const int w    = tid >> 6;
    const int qg   = w & 3;
    const int ms   = w >> 2;       // 0..1
    const int lane = tid & 63;
    const int col  = lane & 31;
    const int hh   = lane >> 5;

    const int lq = l0 + qg * 32 + col;
    const short8 qf = *(const short8*)(qT + ((size_t)(b * L_ + lq)) * D_ + hh * 8);

    float16v oacc[3];
#pragma unroll
    for (int pt = 0; pt < 3; ++pt)
#pragma unroll
      for (int r = 0; r < 16; ++r) oacc[pt][r] = 0.f;
    float lsum = 0.f;

    const unsigned short* kbase =
        kT + ((size_t)(b * L_ + ms * 2048 + col)) * D_ + hh * 8;
    const unsigned short* vtb = v2t + (size_t)b * (L_ / 16) * P_ * 16
                                + (size_t)col * 16 + hh * 8;

    short8 kf_cur = *(const short8*)(kbase);

#pragma unroll 2
    for (int it = 0; it < 64; ++it) {
      const int itn = (it + 1) & 63;               // wrap: always valid
      const short8 kf_nxt = *(const short8*)(kbase + (size_t)itn * 32 * D_);

      float16v zero;
#pragma unroll
      for (int r = 0; r < 16; ++r) zero[r] = 0.f;
      const float16v s = __builtin_amdgcn_mfma_f32_32x32x16_bf16(kf_cur, qf, zero, 0, 0, 0);

      const int mt16 = ms * 128 + it * 2;          // m-tile index (16 m per tile)

#pragma unroll
      for (int mt = 0; mt < 2; ++mt) {
        short8 vf[3];
#pragma unroll
        for (int pt = 0; pt < 3; ++pt)
          vf[pt] = *(const short8*)(vtb + ((size_t)(mt16 + mt) * P_ + pt * 32) * 16);

        unsigned dw[4];
#pragma unroll
        for (int g = 0; g < 4; ++g) {
          const float e0 = __builtin_amdgcn_exp2f(s[8 * mt + 2 * g]);
          const float e1 = __builtin_amdgcn_exp2f(s[8 * mt + 2 * g + 1]);
          lsum += e0 + e1;
          const unsigned u0 = __float_as_uint(e0) + 0x8000u;
          const unsigned u1 = __float_as_uint(e1) + 0x8000u;
          dw[g] = __builtin_amdgcn_perm(u1, u0, 0x07060302u);  // (bf(e1)<<16)|bf(e0)
        }

        const unsigned t0 = hh ? dw[0] : dw[2];
        const unsigned t1 = hh ? dw[1] : dw[3];
        const unsigned r0 = (unsigned)__shfl_xor((int)t0, 32);
        const unsigned r1 = (unsigned)__shfl_xor((int)t1, 32);
        union { int4 i; short8 s8; } pu;
        pu.i.x = hh ? (int)r0 : (int)dw[0];
        pu.i.y = hh ? (int)r1 : (int)dw[1];
        pu.i.z = hh ? (int)dw[2] : (int)r0;
        pu.i.w = hh ? (int)dw[3] : (int)r1;
        const short8 pf = pu.s8;
#pragma unroll
        for (int pt = 0; pt < 3; ++pt)
          oacc[pt] = __builtin_amdgcn_mfma_f32_32x32x16_bf16(vf[pt], pf, oacc[pt], 0, 0, 0);
      }
      kf_cur = kf_nxt;
    }

    atomicAdd(&ldsL[qg * 32 + col], lsum);
#pragma unroll
    for (int pt = 0; pt < 3; ++pt)
#pragma unroll
      for (int r = 0; r < 16; ++r) {
        const int p = (r & 3) + 8 * (r >> 2) + 4 * hh + 32 * pt;
        atomicAdd(&ldsO[p * 128 + qg * 32 + col], oacc[pt][r]);
      }
    __syncthreads();

#pragma unroll
    for (int i = 0; i < 24; ++i) {
      const int idx = tid + i * 512;
      const int p = idx >> 7;
      const int l = idx & 127;
      y[((size_t)(b * P_ + p)) * L_ + l0 + l] = ldsO[idx] / ldsL[l] + b2[p];
    }
  }
}

// ===========================================================================
// FALLBACK PATH: the verified 5-kernel pipeline (unchanged from round 1).
// Used only if hipLaunchCooperativeKernel refuses the launch.
// ===========================================================================
__global__ __launch_bounds__(128) void k_prep(
    const float* __restrict__ Wq, const float* __restrict__ bq,
    const float* __restrict__ Wk, const float* __restrict__ bk,
    const float* __restrict__ Wv, const float* __restrict__ bv,
    const float* __restrict__ W2,
    float* __restrict__ wallT, float* __restrict__ ball)
{
  const int r = blockIdx.x;
  const int c = threadIdx.x;
  float wv;
  if (r < 16) {
    wv = Wq[r * C_ + c];
  } else if (r < 32) {
    wv = Wk[(r - 16) * C_ + c];
  } else {
    const int p = r - 32;
    float s = 0.f;
#pragma unroll 8
    for (int o = 0; o < C_; ++o) s += W2[p * C_ + o] * Wv[o * C_ + c];
    wv = s;
  }
  wallT[c * C_ + r] = wv;
  if (c == 0) {
    float bb;
    if (r < 16)      bb = bq[r];
    else if (r < 32) bb = bk[r - 16];
    else {
      const int p = r - 32;
      float s = 0.f;
#pragma unroll 8
      for (int o = 0; o < C_; ++o) s += W2[p * C_ + o] * bv[o];
      bb = s;
    }
    ball[r] = bb;
  }
}

__global__ __launch_bounds__(512) void k_conv(
    const float* __restrict__ x, const float* __restrict__ Wt,
    float* __restrict__ h, float* __restrict__ psum, float* __restrict__ psumsq)
{
  __shared__ float4 xs4[256];
  __shared__ float rs1[8], rs2[8];
  const int tid = threadIdx.x;
  const int o = blockIdx.y;
  const int l = blockIdx.x * 2048 + tid * 4;

  if (tid < 256) xs4[tid] = ((const float4*)x)[tid];
  __syncthreads();

  float4 acc[8];
#pragma unroll
  for (int bb = 0; bb < 8; ++bb) acc[bb] = (float4){0.f, 0.f, 0.f, 0.f};

  const float* wp = Wt + (size_t)o * L_ + l;
  const size_t stride = (size_t)C_ * L_;
  const int phase = (blockIdx.y + blockIdx.x * 8) & 31;

  float4 wbuf[2][4];
#pragma unroll
  for (int q = 0; q < 4; ++q)
    wbuf[0][q] = *(const float4*)(wp + (size_t)(phase * 4 + q) * stride);

#pragma unroll 2
  for (int g = 0; g < 32; ++g) {
    const int cur = g & 1, nb = cur ^ 1;
    const int in4 = ((phase + g + 1) & 31) * 4;
#pragma unroll
    for (int q = 0; q < 4; ++q)
      wbuf[nb][q] = *(const float4*)(wp + (size_t)(in4 + q) * stride);

    const int ic = (phase + g) & 31;
#pragma unroll
    for (int bb = 0; bb < 8; ++bb) {
      const float4 xb = xs4[bb * 32 + ic];
      acc[bb].x += xb.x * wbuf[cur][0].x + xb.y * wbuf[cur][1].x + xb.z * wbuf[cur][2].x + xb.w * wbuf[cur][3].x;
      acc[bb].y += xb.x * wbuf[cur][0].y + xb.y * wbuf[cur][1].y + xb.z * wbuf[cur][2].y + xb.w * wbuf[cur][3].y;
      acc[bb].z += xb.x * wbuf[cur][0].z + xb.y * wbuf[cur][1].z + xb.z * wbuf[cur][2].z + xb.w * wbuf[cur][3].z;
      acc[bb].w += xb.x * wbuf[cur][0].w + xb.y * wbuf[cur][1].w + xb.z * wbuf[cur][2].w + xb.w * wbuf[cur][3].w;
    }
  }
  float s1 = 0.f, s2 = 0.f;
#pragma unroll
  for (int bb = 0; bb < 8; ++bb) {
    *(float4*)(h + ((size_t)(bb * C_ + o)) * L_ + l) = acc[bb];
    s1 += acc[bb].x + acc[bb].y + acc[bb].z + acc[bb].w;
    s2 += acc[bb].x * acc[bb].x + acc[bb].y * acc[bb].y
        + acc[bb].z * acc[bb].z + acc[bb].w * acc[bb].w;
  }
  for (int off = 1; off < 64; off <<= 1) {
    s1 += __shfl_xor(s1, off);
    s2 += __shfl_xor(s2, off);
  }
  if ((tid & 63) == 0) { rs1[tid >> 6] = s1; rs2[tid >> 6] = s2; }
  __syncthreads();
  if (tid == 0) {
    float a1 = 0.f, a2 = 0.f;
#pragma unroll
    for (int wv = 0; wv < 8; ++wv) { a1 += rs1[wv]; a2 += rs2[wv]; }
    psum[o * 2 + blockIdx.x]   = a1;
    psumsq[o * 2 + blockIdx.x] = a2;
  }
}

__global__ __launch_bounds__(128) void k_bn(
    const float* __restrict__ psum, const float* __restrict__ psumsq,
    const float* __restrict__ gamma, const float* __restrict__ beta,
    float* __restrict__ scale, float* __restrict__ shift)
{
  const int c = threadIdx.x;
  float s1 = 0.f, s2 = 0.f;
  for (int t = 0; t < 2; ++t) { s1 += psum[c * 2 + t]; s2 += psumsq[c * 2 + t]; }
  const float inv = 1.f / 32768.f;
  const float mean = s1 * inv;
  const float var  = s2 * inv - mean * mean;
  const float sc   = rsqrtf(var + 1e-5f) * gamma[c];
  scale[c] = sc;
  shift[c] = beta[c] - mean * sc;
}

__global__ __launch_bounds__(256) void k_proj(
    const float* __restrict__ h, const float* __restrict__ scale,
    const float* __restrict__ shift, const float* __restrict__ wallT,
    const float* __restrict__ ball,
    unsigned short* __restrict__ qT, unsigned short* __restrict__ kT,
    unsigned short* __restrict__ v2t)
{
  __shared__ __align__(16) char sm[128 * 68 * 4];
  float* hn = (float*)sm;
  unsigned short* v2s = (unsigned short*)sm;

  const int b = blockIdx.y;
  const int l0 = blockIdx.x * 64;
  const int tid = threadIdx.x;

#pragma unroll
  for (int i = 0; i < 8; ++i) {
    const int idx = tid + i * 256;
    const int c = idx >> 4, lq = (idx & 15) * 4;
    const float4 hv = *(const float4*)(h + ((size_t)(b * C_ + c)) * L_ + l0 + lq);
    const float sc = scale[c], sh = shift[c];
    float4 r;
    r.x = fmaxf(hv.x * sc + sh, 0.f);
    r.y = fmaxf(hv.y * sc + sh, 0.f);
    r.z = fmaxf(hv.z * sc + sh, 0.f);
    r.w = fmaxf(hv.w * sc + sh, 0.f);
    *(float4*)(hn + c * 68 + lq) = r;
  }
  __syncthreads();

  const int wu = __builtin_amdgcn_readfirstlane(tid) >> 6;
  const int lane = tid & 63;
  const int l = l0 + lane;

  float acc[32];
#pragma unroll
  for (int r = 0; r < 32; ++r) acc[r] = ball[wu * 32 + r];

#pragma unroll 4
  for (int c = 0; c < C_; ++c) {
    const float hv = hn[c * 68 + lane];
    const float* wrow = wallT + c * C_ + wu * 32;
#pragma unroll
    for (int r = 0; r < 32; ++r) acc[r] += wrow[r] * hv;
  }
  __syncthreads();

  if (wu == 0) {
    const size_t row = (size_t)(b * L_ + l) * D_;
    short8 v0, v1;
#pragma unroll
    for (int r = 0; r < 8; ++r) {
      v0[r] = (short)f2bf(acc[r] * 1.44269504f);
      v1[r] = (short)f2bf(acc[8 + r] * 1.44269504f);
    }
    *(short8*)(qT + row) = v0;  *(short8*)(qT + row + 8) = v1;
#pragma unroll
    for (int r = 0; r < 8; ++r) { v0[r] = (short)f2bf(acc[16 + r]); v1[r] = (short)f2bf(acc[24 + r]); }
    *(short8*)(kT + row) = v0;  *(short8*)(kT + row + 8) = v1;
  } else {
    const int pbase = wu * 32 - 32;
#pragma unroll
    for (int r = 0; r < 32; ++r)
      v2s[(pbase + r) * 72 + lane] = f2bf(acc[r]);
  }
  __syncthreads();

#pragma unroll
  for (int i = 0; i < 6; ++i) {
    const int j = tid + i * 256;
    const int mo4 = j & 3;
    const int jp = j >> 2;
    const int p = jp % 96;
    const int mtl = jp / 96;
    const uint2 val = *(const uint2*)(v2s + p * 72 + mtl * 16 + mo4 * 4);
    *(uint2*)(v2t + ((size_t)((b * (L_ / 16) + blockIdx.x * 4 + mtl)) * P_ + p) * 16
              + mo4 * 4) = val;
  }
}

__global__ __launch_bounds__(1024, 4) void k_attn(
    const unsigned short* __restrict__ qT, const unsigned short* __restrict__ kT,
    const unsigned short* __restrict__ v2t, const float* __restrict__ b2,
    float* __restrict__ y)
{
  __shared__ float ldsO[P_ * 128];
  __shared__ float ldsL[128];

  const int b = blockIdx.y;
  const int l0 = blockIdx.x * 128;
  const int tid = threadIdx.x;
  const int w  = tid >> 6;
  const int qg = w & 3;
  const int ms = w >> 2;
  const int lane = tid & 63;
  const int col = lane & 31;
  const int hh  = lane >> 5;

#pragma unroll
  for (int i = 0; i < 12; ++i) ldsO[tid + i * 1024] = 0.f;
  if (tid < 128) ldsL[tid] = 0.f;
  __syncthreads();

  const int lq = l0 + qg * 32 + col;
  const short8 qf = *(const short8*)(qT + ((size_t)(b * L_ + lq)) * D_ + hh * 8);

  float16v oacc[3];
#pragma unroll
  for (int pt = 0; pt < 3; ++pt)
#pragma unroll
    for (int r = 0; r < 16; ++r) oacc[pt][r] = 0.f;
  float lsum = 0.f;

  const unsigned short* kbase =
      kT + ((size_t)(b * L_ + ms * 1024 + col)) * D_ + hh * 8;
  const unsigned short* vtb = v2t + (size_t)b * (L_ / 16) * P_ * 16
                              + (size_t)col * 16 + hh * 8;

  short8 kf_cur = *(const short8*)(kbase);

#pragma unroll 2
  for (int it = 0; it < 32; ++it) {
    const int itn = (it + 1) & 31;
    const short8 kf_nxt = *(const short8*)(kbase + (size_t)itn * 32 * D_);

    float16v zero;
#pragma unroll
    for (int r = 0; r < 16; ++r) zero[r] = 0.f;
    const float16v s = __builtin_amdgcn_mfma_f32_32x32x16_bf16(kf_cur, qf, zero, 0, 0, 0);

    const int mt16 = ms * 64 + it * 2;

#pragma unroll
    for (int mt = 0; mt < 2; ++mt) {
      short8 vf[3];
#pragma unroll
      for (int pt = 0; pt < 3; ++pt)
        vf[pt] = *(const short8*)(vtb + ((size_t)(mt16 + mt) * P_ + pt * 32) * 16);

      unsigned dw[4];
#pragma unroll
      for (int g = 0; g < 4; ++g) {
        const float e0 = __builtin_amdgcn_exp2f(s[8 * mt + 2 * g]);
        const float e1 = __builtin_amdgcn_exp2f(s[8 * mt + 2 * g + 1]);
        lsum += e0 + e1;
        const unsigned u0 = __float_as_uint(e0) + 0x8000u;
        const unsigned u1 = __float_as_uint(e1) + 0x8000u;
        dw[g] = __builtin_amdgcn_perm(u1, u0, 0x07060302u);
      }

      const unsigned t0 = hh ? dw[0] : dw[2];
      const unsigned t1 = hh ? dw[1] : dw[3];
      const unsigned r0 = (unsigned)__shfl_xor((int)t0, 32);
      const unsigned r1 = (unsigned)__shfl_xor((int)t1, 32);
      union { int4 i; short8 s8; } pu;
      pu.i.x = hh ? (int)r0 : (int)dw[0];
      pu.i.y = hh ? (int)r1 : (int)dw[1];
      pu.i.z = hh ? (int)dw[2] : (int)r0;
      pu.i.w = hh ? (int)dw[3] : (int)r1;
      const short8 pf = pu.s8;
#pragma unroll
      for (int pt = 0; pt < 3; ++pt)
        oacc[pt] = __builtin_amdgcn_mfma_f32_32x32x16_bf16(vf[mt * 0 + pt], pf, oacc[pt], 0, 0, 0);
    }
    kf_cur = kf_nxt;
  }

  atomicAdd(&ldsL[qg * 32 + col], lsum);
#pragma unroll
  for (int pt = 0; pt < 3; ++pt)
#pragma unroll
    for (int r = 0; r < 16; ++r) {
      const int p = (r & 3) + 8 * (r >> 2) + 4 * hh + 32 * pt;
      atomicAdd(&ldsO[p * 128 + qg * 32 + col], oacc[pt][r]);
    }
  __syncthreads();

#pragma unroll
  for (int i = 0; i < 12; ++i) {
    const int idx = tid + i * 1024;
    const int p = idx >> 7;
    const int l = idx & 127;
    y[((size_t)(b * P_ + p)) * L_ + l0 + l] = ldsO[idx] / ldsL[l] + b2[p];
  }
}

// ---------------------------------------------------------------------------
extern "C" void kernel_launch(void* const* d_in, const int* in_sizes, int n_in,
                              void* d_out, int out_size, void* d_ws, size_t ws_size,
                              hipStream_t stream) {
  (void)in_sizes; (void)n_in; (void)out_size; (void)ws_size;
  const float* x     = (const float*)d_in[0];
  const float* Wt    = (const float*)d_in[1];
  // d_in[2] = bt: unused — BatchNorm mean-subtraction cancels it exactly.
  const float* gamma = (const float*)d_in[3];
  const float* beta  = (const float*)d_in[4];
  const float* Wq    = (const float*)d_in[5];
  const float* bq    = (const float*)d_in[6];
  const float* Wk    = (const float*)d_in[7];
  const float* bk    = (const float*)d_in[8];
  const float* Wv    = (const float*)d_in[9];
  const float* bv    = (const float*)d_in[10];
  const float* W2    = (const float*)d_in[11];
  const float* b2    = (const float*)d_in[12];
  float* y = (float*)d_out;

  char* ws = (char*)d_ws;
  float* h       = (float*)(ws + OFF_H);
  float* psum    = (float*)(ws + OFF_PSUM);
  float* psumsq  = (float*)(ws + OFF_PSUMSQ);
  float* scale   = (float*)(ws + OFF_SCALE);
  float* shift   = (float*)(ws + OFF_SHIFT);
  float* wallT   = (float*)(ws + OFF_WALLT);
  float* ball    = (float*)(ws + OFF_BALL);
  unsigned short* qT  = (unsigned short*)(ws + OFF_QT);
  unsigned short* kT  = (unsigned short*)(ws + OFF_KT);
  unsigned short* v2t = (unsigned short*)(ws + OFF_V2);

  void* kargs[] = {
      (void*)&x, (void*)&Wt, (void*)&gamma, (void*)&beta,
      (void*)&Wq, (void*)&bq, (void*)&Wk, (void*)&bk,
      (void*)&Wv, (void*)&bv, (void*)&W2, (void*)&b2,
      (void*)&y, (void*)&h, (void*)&psum, (void*)&psumsq,
      (void*)&wallT, (void*)&ball, (void*)&qT, (void*)&kT, (void*)&v2t};
  const hipError_t cerr = hipLaunchCooperativeKernel(
      (const void*)k_fused, dim3(256), dim3(512), kargs, 0, stream);

  if (cerr != hipSuccess) {
    // Fallback: verified 5-kernel pipeline.
    k_prep<<<128, 128, 0, stream>>>(Wq, bq, Wk, bk, Wv, bv, W2, wallT, ball);
    k_conv<<<dim3(2, 128), 512, 0, stream>>>(x, Wt, h, psum, psumsq);
    k_bn<<<1, 128, 0, stream>>>(psum, psumsq, gamma, beta, scale, shift);
    k_proj<<<dim3(64, 8), 256, 0, stream>>>(h, scale, shift, wallT, ball, qT, kT, v2t);
    k_attn<<<dim3(32, 8), 1024, 0, stream>>>(qT, kT, v2t, b2, y);
  }
}